// Round 1
// baseline (22.070 us; speedup 1.0000x reference)
//
#include <hip/hip_runtime.h>

// RNG_VARIANT:
//   0 = partitionable threefry (JAX >= 0.5 default): x=(hi(i)=0, lo(i)=i), bits = y0 ^ y1
//   1 = original iota-split:   pair j: x=(j, 512+j), bits[j]=y0, bits[512+j]=y1
//   2 = partitionable, bits = y0 only
//   3 = partitionable, swapped counter words: x=(i, 0), bits = y0 ^ y1
#define RNG_VARIANT 0

constexpr int PP = 16;       // patch
constexpr int NSEL = 128;    // N
constexpr int B = 4, C = 3, H = 256, W = 256;
constexpr int L = 256;       // patches per batch (16x16)

__device__ __forceinline__ unsigned rotl32(unsigned x, int d) {
  return (x << d) | (x >> (32 - d));
}

// Threefry-2x32, 20 rounds (Random123 / JAX).
__device__ __forceinline__ void threefry2x32(unsigned k0, unsigned k1,
                                             unsigned& x0, unsigned& x1) {
  unsigned ks[3] = {k0, k1, k0 ^ k1 ^ 0x1BD11BDAu};
  x0 += ks[0];
  x1 += ks[1];
  const int rot[2][4] = {{13, 15, 26, 6}, {17, 29, 16, 24}};
#pragma unroll
  for (int i = 0; i < 5; ++i) {
    const int* r = rot[i & 1];
#pragma unroll
    for (int j = 0; j < 4; ++j) {
      x0 += x1;
      x1 = rotl32(x1, r[j]);
      x1 ^= x0;
    }
    x0 += ks[(i + 1) % 3];
    x1 += ks[(i + 2) % 3] + (unsigned)(i + 1);
  }
}

// One wave (64 threads) per patch: sum the 16x16 mask window.
__global__ void mask_sum_kernel(const float* __restrict__ mask,
                                float* __restrict__ msum) {
  int p = blockIdx.x;          // b*256 + l
  int b = p >> 8, l = p & 255;
  int ri = (l >> 4) << 4, ci = (l & 15) << 4;
  int t = threadIdx.x;         // 0..63
  int r = t >> 2, c4 = (t & 3) << 2;
  const float4 v = *reinterpret_cast<const float4*>(
      mask + ((size_t)b * H + ri + r) * W + ci + c4);
  float s = v.x + v.y + v.z + v.w;
#pragma unroll
  for (int off = 32; off > 0; off >>= 1) s += __shfl_down(s, off);
  if (t == 0) msum[p] = s;
}

// One block per batch; thread l = patch l. Rank by (bits>>9) with stable
// tie-break (lower index first), invalid patches below all valid ones.
// Selected set enumerated in ascending l == jnp.sort(top_k indices).
__global__ void select_kernel(const float* __restrict__ msum,
                              int* __restrict__ idx_out) {
  int b = blockIdx.x;   // 0..3
  int l = threadIdx.x;  // 0..255
  int i = b * L + l;

  unsigned bits;
#if RNG_VARIANT == 0
  {
    unsigned x0 = 0u, x1 = (unsigned)i;
    threefry2x32(0u, 42u, x0, x1);
    bits = x0 ^ x1;
  }
#elif RNG_VARIANT == 1
  {
    int j = (i < 512) ? i : i - 512;
    unsigned x0 = (unsigned)j, x1 = (unsigned)(512 + j);
    threefry2x32(0u, 42u, x0, x1);
    bits = (i < 512) ? x0 : x1;
  }
#elif RNG_VARIANT == 2
  {
    unsigned x0 = 0u, x1 = (unsigned)i;
    threefry2x32(0u, 42u, x0, x1);
    bits = x0;
  }
#else
  {
    unsigned x0 = (unsigned)i, x1 = 0u;
    threefry2x32(0u, 42u, x0, x1);
    bits = x0 ^ x1;
  }
#endif

  // valid iff mean(mask patch) >= 1.0
  bool valid = (msum[i] * (1.0f / 256.0f)) >= 1.0f;
  // score in [1, 2^23] for valid (monotone in gumbel), 0 for invalid (-inf).
  unsigned score = valid ? ((bits >> 9) + 1u) : 0u;

  __shared__ unsigned s_score[L];
  __shared__ unsigned char s_sel[L];
  s_score[l] = score;
  __syncthreads();

  int rank = 0;
  for (int m = 0; m < L; ++m) {
    unsigned sm = s_score[m];
    rank += (sm > score) || (sm == score && m < l);
  }
  int selected = (rank < NSEL) ? 1 : 0;
  s_sel[l] = (unsigned char)selected;
  __syncthreads();

  if (selected) {
    int slot = 0;
    for (int m = 0; m < l; ++m) slot += s_sel[m];
    idx_out[b * NSEL + slot] = l;
  }
}

// One thread per output float4. Out layout: x_sample [4,128,768] then
// pos_sample [4,128,512], both float32, within-patch order d = c*256+pr*16+pc.
__global__ void gather_kernel(const float* __restrict__ x,
                              const float* __restrict__ pos,
                              const int* __restrict__ idx,
                              float4* __restrict__ out) {
  int t = blockIdx.x * blockDim.x + threadIdx.x;
  const int XQ = B * NSEL * (C * PP * PP) / 4;  // 98304 float4s for x_sample
  if (t < XQ) {
    const int perb = NSEL * 192;  // 768/4 per patch
    int b = t / perb;
    int rem = t - b * perb;
    int n = rem / 192;
    int q = rem - n * 192;
    int d = q << 2;        // 0..764, step 4
    int c = d >> 8;        // channel 0..2
    int dd = d & 255;
    int pr = dd >> 4;
    int pc = dd & 15;      // multiple of 4
    int id = idx[b * NSEL + n];
    int ri = (id >> 4) << 4, ci = (id & 15) << 4;
    out[t] = *reinterpret_cast<const float4*>(
        x + (((size_t)(b * C + c)) * H + ri + pr) * W + ci + pc);
  } else {
    int u = t - XQ;
    const int perb = NSEL * 128;  // 512/4 per patch
    int b = u / perb;
    int rem = u - b * perb;
    int n = rem / 128;
    int q = rem - n * 128;
    int d = q << 2;
    int ch = d >> 8;       // 0 or 1 (first ceil(512/256)=2 channels of pos)
    int dd = d & 255;
    int pr = dd >> 4;
    int pc = dd & 15;
    int id = idx[b * NSEL + n];
    int ri = (id >> 4) << 4, ci = (id & 15) << 4;
    out[XQ + u] = *reinterpret_cast<const float4*>(
        pos + (((size_t)(b * 512 + ch)) * H + ri + pr) * W + ci + pc);
  }
}

extern "C" void kernel_launch(void* const* d_in, const int* in_sizes, int n_in,
                              void* d_out, int out_size, void* d_ws, size_t ws_size,
                              hipStream_t stream) {
  const float* x = (const float*)d_in[0];     // [4,3,256,256]
  const float* mask = (const float*)d_in[1];  // [4,1,256,256]
  const float* pos = (const float*)d_in[2];   // [4,512,256,256]
  float* msum = (float*)d_ws;                       // 1024 floats
  int* idx = (int*)((char*)d_ws + 4096);            // 512 ints

  mask_sum_kernel<<<B * L, 64, 0, stream>>>(mask, msum);
  select_kernel<<<B, L, 0, stream>>>(msum, idx);

  const int total_f4 = (B * NSEL * (C * PP * PP) + B * NSEL * 512) / 4;  // 163840
  gather_kernel<<<(total_f4 + 255) / 256, 256, 0, stream>>>(
      x, pos, idx, (float4*)d_out);
}

// Round 2
// 19.952 us; speedup vs baseline: 1.1061x; 1.1061x over previous
//
#include <hip/hip_runtime.h>

constexpr int PP = 16;       // patch
constexpr int NSEL = 128;    // N
constexpr int B = 4, C = 3, H = 256, W = 256;
constexpr int L = 256;       // patches per batch (16x16)

__device__ __forceinline__ unsigned rotl32(unsigned x, int d) {
  return (x << d) | (x >> (32 - d));
}

// Threefry-2x32, 20 rounds (Random123 / JAX), key=(0,42), partitionable mode:
// counter=(0, i), output bits = y0 ^ y1. Verified exact vs jax.random.gumbel
// ranking in round 0 (absmax 0.0).
__device__ __forceinline__ void threefry2x32(unsigned k0, unsigned k1,
                                             unsigned& x0, unsigned& x1) {
  unsigned ks[3] = {k0, k1, k0 ^ k1 ^ 0x1BD11BDAu};
  x0 += ks[0];
  x1 += ks[1];
  const int rot[2][4] = {{13, 15, 26, 6}, {17, 29, 16, 24}};
#pragma unroll
  for (int i = 0; i < 5; ++i) {
    const int* r = rot[i & 1];
#pragma unroll
    for (int j = 0; j < 4; ++j) {
      x0 += x1;
      x1 = rotl32(x1, r[j]);
      x1 ^= x0;
    }
    x0 += ks[(i + 1) % 3];
    x1 += ks[(i + 2) % 3] + (unsigned)(i + 1);
  }
}

// One block per batch (4 blocks x 256 threads). Thread l:
//   1) sums its own 16x16 mask patch (64 independent float4 loads),
//   2) threefry -> monotone 23-bit score (0 for invalid patches),
//   3) O(L/4) uint4 rank scan in LDS, select rank < 128,
//   4) ballot/popcount compaction -> idx written in ascending patch order
//      (== jnp.sort(jax.lax.top_k(scores, N)[1])).
__global__ void select_kernel(const float* __restrict__ mask,
                              int* __restrict__ idx_out) {
  int b = blockIdx.x;   // 0..3
  int l = threadIdx.x;  // 0..255
  int ri = (l >> 4) << 4, ci = (l & 15) << 4;

  // --- mask patch sum ---
  const float* base = mask + ((size_t)b * H + ri) * W + ci;
  float s = 0.0f;
#pragma unroll
  for (int r = 0; r < PP; ++r) {
#pragma unroll
    for (int c4 = 0; c4 < 4; ++c4) {
      const float4 v = *reinterpret_cast<const float4*>(base + r * W + c4 * 4);
      s += v.x + v.y + v.z + v.w;
    }
  }
  bool valid = (s * (1.0f / 256.0f)) >= 1.0f;

  // --- gumbel-equivalent score ---
  unsigned x0 = 0u, x1 = (unsigned)(b * L + l);
  threefry2x32(0u, 42u, x0, x1);
  unsigned bits = x0 ^ x1;
  unsigned score = valid ? ((bits >> 9) + 1u) : 0u;

  __shared__ unsigned s_score[L];
  __shared__ int s_wcnt[4];
  s_score[l] = score;
  __syncthreads();

  // --- rank: # of (score', m) strictly better; stable tie-break lower-index ---
  int rank = 0;
  const uint4* sv = reinterpret_cast<const uint4*>(s_score);
#pragma unroll 8
  for (int m4 = 0; m4 < L / 4; ++m4) {
    uint4 v = sv[m4];
    int m = m4 << 2;
    rank += (v.x > score) || (v.x == score && (m + 0) < l);
    rank += (v.y > score) || (v.y == score && (m + 1) < l);
    rank += (v.z > score) || (v.z == score && (m + 2) < l);
    rank += (v.w > score) || (v.w == score && (m + 3) < l);
  }
  bool selected = rank < NSEL;

  // --- compaction via ballot + wave-prefix ---
  unsigned long long mball = __ballot(selected);
  int w = l >> 6, lane = l & 63;
  if (lane == 0) s_wcnt[w] = __popcll(mball);
  __syncthreads();
  int slot = __popcll(mball & ((1ull << lane) - 1ull));
  for (int j = 0; j < 4; ++j) slot += (j < w) ? s_wcnt[j] : 0;
  if (selected) idx_out[b * NSEL + slot] = l;
}

// One thread per output float4. Out layout: x_sample [4,128,768] then
// pos_sample [4,128,512], both float32, within-patch order d = c*256+pr*16+pc.
__global__ void gather_kernel(const float* __restrict__ x,
                              const float* __restrict__ pos,
                              const int* __restrict__ idx,
                              float4* __restrict__ out) {
  int t = blockIdx.x * blockDim.x + threadIdx.x;
  const int XQ = B * NSEL * (C * PP * PP) / 4;  // 98304 float4s for x_sample
  if (t < XQ) {
    const int perb = NSEL * 192;  // 768/4 per patch
    int b = t / perb;
    int rem = t - b * perb;
    int n = rem / 192;
    int q = rem - n * 192;
    int d = q << 2;        // 0..764, step 4
    int c = d >> 8;        // channel 0..2
    int dd = d & 255;
    int pr = dd >> 4;
    int pc = dd & 15;      // multiple of 4
    int id = idx[b * NSEL + n];
    int ri = (id >> 4) << 4, ci = (id & 15) << 4;
    out[t] = *reinterpret_cast<const float4*>(
        x + (((size_t)(b * C + c)) * H + ri + pr) * W + ci + pc);
  } else {
    int u = t - XQ;
    const int perb = NSEL * 128;  // 512/4 per patch
    int b = u / perb;
    int rem = u - b * perb;
    int n = rem / 128;
    int q = rem - n * 128;
    int d = q << 2;
    int ch = d >> 8;       // 0 or 1 (first ceil(512/256)=2 channels of pos)
    int dd = d & 255;
    int pr = dd >> 4;
    int pc = dd & 15;
    int id = idx[b * NSEL + n];
    int ri = (id >> 4) << 4, ci = (id & 15) << 4;
    out[XQ + u] = *reinterpret_cast<const float4*>(
        pos + (((size_t)(b * 512 + ch)) * H + ri + pr) * W + ci + pc);
  }
}

extern "C" void kernel_launch(void* const* d_in, const int* in_sizes, int n_in,
                              void* d_out, int out_size, void* d_ws, size_t ws_size,
                              hipStream_t stream) {
  const float* x = (const float*)d_in[0];     // [4,3,256,256]
  const float* mask = (const float*)d_in[1];  // [4,1,256,256]
  const float* pos = (const float*)d_in[2];   // [4,512,256,256]
  int* idx = (int*)d_ws;                      // 512 ints

  select_kernel<<<B, L, 0, stream>>>(mask, idx);

  const int total_f4 = (B * NSEL * (C * PP * PP) + B * NSEL * 512) / 4;  // 163840
  gather_kernel<<<(total_f4 + 255) / 256, 256, 0, stream>>>(
      x, pos, idx, (float4*)d_out);
}